// Round 6
// baseline (674.840 us; speedup 1.0000x reference)
//
#include <hip/hip_runtime.h>

typedef _Float16 f16;
typedef __attribute__((ext_vector_type(8))) _Float16 f16x8;
typedef __attribute__((ext_vector_type(4))) float f32x4;

#define XS 136            // padded LDS row stride in f16 elems (128 + 8)
#define NEGV (-1e30f)

// ---------- helpers ----------

// async global->LDS, 16B per lane; LDS dest = wave-uniform base + lane*16
__device__ __forceinline__ void gl_lds16(const f16* g, f16* l) {
  __builtin_amdgcn_global_load_lds(
      (const __attribute__((address_space(1))) unsigned int*)(g),
      (__attribute__((address_space(3))) unsigned int*)(l), 16, 0, 0);
}

__device__ __forceinline__ void stage_emb(const int* __restrict__ ids,
                                          const float* __restrict__ emb,
                                          f16* Xs, int tid) {
  // rows x 128 f32 -> f16 LDS. thread: row tid/4 (wave-private rows:
  // wave w stages exactly rows [16w,16w+16)).
  int t = tid >> 2, seg = tid & 3;
  int id = ids[t];
  const float4* src = (const float4*)(emb + (size_t)id * 128 + seg * 32);
  f16x8* dst = (f16x8*)(Xs + t * XS + seg * 32);
#pragma unroll
  for (int i = 0; i < 4; ++i) {
    float4 v0 = src[2 * i], v1 = src[2 * i + 1];
    f16x8 o;
    o[0] = (f16)v0.x; o[1] = (f16)v0.y; o[2] = (f16)v0.z; o[3] = (f16)v0.w;
    o[4] = (f16)v1.x; o[5] = (f16)v1.y; o[6] = (f16)v1.z; o[7] = (f16)v1.w;
    dst[i] = o;
  }
}

__device__ __forceinline__ void load_afrag(f16x8* afrag, const f16* Xs,
                                           int wave, int lane) {
  const int r = lane & 15, quad = lane >> 4;
#pragma unroll
  for (int k = 0; k < 4; ++k)
    afrag[k] = *(const f16x8*)(Xs + (wave * 16 + r) * XS + quad * 8 + k * 32);
}

// layer GEMM, B-fragments from LDS (conflict-free contiguous ds_read_b128)
__device__ __forceinline__ void layer_mfma_lds(f32x4* acc, const f16x8* afrag,
                                               const f16* Ws, int lane) {
  const f16* Wl = Ws + lane * 8;
#pragma unroll
  for (int nt = 0; nt < 8; ++nt) {
    f32x4 c = {0.f, 0.f, 0.f, 0.f};
#pragma unroll
    for (int k = 0; k < 4; ++k) {
      f16x8 b = *(const f16x8*)(Wl + (nt * 4 + k) * 512);
      c = __builtin_amdgcn_mfma_f32_16x16x32_f16(afrag[k], b, c, 0, 0, 0);
    }
    acc[nt] = c;
  }
}

// layer GEMM, B-fragments streamed from global (32KB stream -> L1-resident)
__device__ __forceinline__ void layer_mfma_glb(f32x4* acc, const f16x8* afrag,
                                               const f16* __restrict__ Wf, int lane) {
  const f16* Wl = Wf + lane * 8;
#pragma unroll
  for (int nt = 0; nt < 8; ++nt) {
    f32x4 c = {0.f, 0.f, 0.f, 0.f};
#pragma unroll
    for (int k = 0; k < 4; ++k) {
      f16x8 b = *(const f16x8*)(Wl + (nt * 4 + k) * 512);
      c = __builtin_amdgcn_mfma_f32_16x16x32_f16(afrag[k], b, c, 0, 0, 0);
    }
    acc[nt] = c;
  }
}

// layer GEMM, B-fragments gathered inline from f32 W[k][n] (slow path; only
// used by the 64 qencode blocks, which are latency-tolerant).
__device__ __forceinline__ void layer_mfma_inline(f32x4* acc, const f16x8* afrag,
                                                  const float* __restrict__ W,
                                                  int lane) {
  const int r = lane & 15, quad = lane >> 4;
#pragma unroll
  for (int nt = 0; nt < 8; ++nt) {
    f32x4 c = {0.f, 0.f, 0.f, 0.f};
#pragma unroll
    for (int k = 0; k < 4; ++k) {
      const float* src = W + (k * 32 + quad * 8) * 128 + nt * 16 + r;
      f16x8 b;
#pragma unroll
      for (int j = 0; j < 8; ++j) b[j] = (f16)src[j * 128];
      c = __builtin_amdgcn_mfma_f32_16x16x32_f16(afrag[k], b, c, 0, 0, 0);
    }
    acc[nt] = c;
  }
}

// bias + relu + layernorm, write h back to Xs (wave-private rows)
__device__ __forceinline__ void epilogue_ln(f32x4* acc, int wave, int lane, f16* Xs,
                                            const float* __restrict__ bias,
                                            const float* __restrict__ lnw,
                                            const float* __restrict__ lnb) {
  const int r = lane & 15, quad = lane >> 4;
  float s1[4] = {0, 0, 0, 0}, s2[4] = {0, 0, 0, 0};
#pragma unroll
  for (int nt = 0; nt < 8; ++nt) {
    float bv = bias[nt * 16 + r];
#pragma unroll
    for (int g = 0; g < 4; ++g) {
      float z = fmaxf(acc[nt][g] + bv, 0.f);
      acc[nt][g] = z; s1[g] += z; s2[g] += z * z;
    }
  }
#pragma unroll
  for (int off = 1; off < 16; off <<= 1) {
#pragma unroll
    for (int g = 0; g < 4; ++g) {
      s1[g] += __shfl_xor(s1[g], off);
      s2[g] += __shfl_xor(s2[g], off);
    }
  }
  float mean[4], rstd[4];
#pragma unroll
  for (int g = 0; g < 4; ++g) {
    mean[g] = s1[g] * (1.f / 128.f);
    rstd[g] = rsqrtf(s2[g] * (1.f / 128.f) - mean[g] * mean[g] + 1e-5f);
  }
#pragma unroll
  for (int nt = 0; nt < 8; ++nt) {
    float w = lnw[nt * 16 + r], bb = lnb[nt * 16 + r];
#pragma unroll
    for (int g = 0; g < 4; ++g) {
      float h = (acc[nt][g] - mean[g]) * rstd[g] * w + bb;
      Xs[(wave * 16 + quad * 4 + g) * XS + nt * 16 + r] = (f16)h;
    }
  }
}

// ---------- kernels ----------

// Fused setup: blocks 0..15 transform d-side W -> fragment order (f16);
// blocks 16..79 encode the 64 query batches (W gathered inline from f32).
__global__ __launch_bounds__(256) void setup_kernel(
    const float* __restrict__ dW1, const float* __restrict__ dW2,
    const int* __restrict__ qids, const int* __restrict__ qmask,
    const float* __restrict__ emb,
    const float* __restrict__ qW1, const float* __restrict__ b1,
    const float* __restrict__ qW2, const float* __restrict__ b2,
    const float* __restrict__ lnw, const float* __restrict__ lnb,
    f16* __restrict__ wts, f16* __restrict__ qv) {
  __shared__ __align__(16) f16 Xs[64 * XS];
  const int tid = threadIdx.x;
  if (blockIdx.x < 16) {
    // prep: W[k][n] f32 -> out[((nt*4+k)*64 + quad*16 + r)*8 + j]
    int mat = blockIdx.x >> 3, blk = blockIdx.x & 7;
    const float* W = mat == 0 ? dW1 : dW2;
    int u = blk * 256 + tid;
    int r = u & 15, quad = (u >> 4) & 3, k = (u >> 6) & 3, nt = u >> 8;
    const float* src = W + (k * 32 + quad * 8) * 128 + nt * 16 + r;
    f16x8 o;
#pragma unroll
    for (int j = 0; j < 8; ++j) o[j] = (f16)src[j * 128];
    *(f16x8*)(wts + (size_t)mat * 16384 + (size_t)u * 8) = o;
    return;
  }
  // qencode
  const int wave = tid >> 6, lane = tid & 63;
  const int b = blockIdx.x - 16;
  stage_emb(qids + b * 64, emb, Xs, tid);
  f32x4 acc[8];
  f16x8 afrag[4];
  load_afrag(afrag, Xs, wave, lane);          // own rows — no barrier
  layer_mfma_inline(acc, afrag, qW1, lane);
  epilogue_ln(acc, wave, lane, Xs, b1, lnw, lnb);
  load_afrag(afrag, Xs, wave, lane);
  layer_mfma_inline(acc, afrag, qW2, lane);
  epilogue_ln(acc, wave, lane, Xs, b2, lnw, lnb);
  __syncthreads();                            // copy-out reads all rows
  // masked copy-out in A-fragment order: qv[b][u][8]
#pragma unroll
  for (int i = 0; i < 4; ++i) {
    int u = tid + i * 256;               // 1024 units of f16x8
    int r = u & 15, quad = (u >> 4) & 3, k = (u >> 6) & 3, mt = u >> 8;
    int row = mt * 16 + r;
    f16 m = (f16)(float)qmask[b * 64 + row];
    f16x8 v = *(const f16x8*)(Xs + row * XS + k * 32 + quad * 8);
#pragma unroll
    for (int j = 0; j < 8; ++j) v[j] = v[j] * m;
    *(f16x8*)(qv + (size_t)b * 8192 + (size_t)u * 8) = v;
  }
}

// 512 threads / 8 waves, one 128-doc tile per block (2048 blocks).
// W1 resident in LDS (staged once), W2 streamed via L1. 2 barriers.
// Last block per batch folds the final max/sum reduction.
__global__ __launch_bounds__(512, 4) void docsim_kernel(
    const int* __restrict__ dids, const int* __restrict__ dmask,
    const float* __restrict__ emb,
    const f16* __restrict__ W1f, const float* __restrict__ b1,
    const f16* __restrict__ W2f, const float* __restrict__ b2,
    const float* __restrict__ lnw, const float* __restrict__ lnb,
    const f16* __restrict__ qv, float* __restrict__ partials,
    int* __restrict__ counters, float* __restrict__ out) {
  __shared__ __align__(16) f16 Xs[128 * XS];  // 34,816 B
  __shared__ __align__(16) f16 Ws[16384];     // 32,768 B — W1 resident
  __shared__ int lastflag;
  const int tid = threadIdx.x, wave = tid >> 6, lane = tid & 63;
  const int b = blockIdx.x >> 5;              // batch (2048 = 64 x 32)
  const int dc0 = (blockIdx.x & 31) * 2;      // first of 2 doc chunks
  const int g = wave >> 2;                    // chunk within block (0/1)
  const int qt = wave & 3;                    // q-row tile for sim
  const int r = lane & 15, quad = lane >> 4;
  // doc-mask for this lane's sim columns — independent early loads
  float mv[4];
#pragma unroll
  for (int nt = 0; nt < 4; ++nt)
    mv[nt] = (float)dmask[(size_t)b * 4096 + (dc0 + g) * 64 + nt * 16 + r];
  // sim A-fragments (fragment-ordered qv) — early, independent
  f16x8 qfrag[4];
#pragma unroll
  for (int k = 0; k < 4; ++k) {
    int u = (qt * 4 + k) * 64 + quad * 16 + r;
    qfrag[k] = *(const f16x8*)(qv + (size_t)b * 8192 + (size_t)u * 8);
  }
  // stage W1 into LDS: 32 chunks of 1KB, 4 per wave (async DMA)
#pragma unroll
  for (int c = 0; c < 4; ++c) {
    int chunk = wave * 4 + c;
    gl_lds16(W1f + chunk * 512 + lane * 8, Ws + chunk * 512);
  }
  // emb gather: 128 rows, wave-private
  stage_emb(dids + (size_t)b * 4096 + dc0 * 64, emb, Xs, tid);
  __syncthreads();                            // Ws + (own rows already ok)
  f32x4 acc[8];
  f16x8 afrag[4];
  load_afrag(afrag, Xs, wave, lane);
  layer_mfma_lds(acc, afrag, Ws, lane);       // W1 from LDS
  epilogue_ln(acc, wave, lane, Xs, b1, lnw, lnb);
  load_afrag(afrag, Xs, wave, lane);
  layer_mfma_glb(acc, afrag, W2f, lane);      // W2 from global (L1-resident)
  epilogue_ln(acc, wave, lane, Xs, b2, lnw, lnb);
  __syncthreads();                            // dv (128 rows) all-visible
  float rowmax[4] = {NEGV, NEGV, NEGV, NEGV};
#pragma unroll
  for (int nt = 0; nt < 4; ++nt) {
    f32x4 c = {0.f, 0.f, 0.f, 0.f};
#pragma unroll
    for (int k = 0; k < 4; ++k) {
      f16x8 bfrag = *(const f16x8*)(Xs + (g * 64 + nt * 16 + r) * XS + quad * 8 + k * 32);
      c = __builtin_amdgcn_mfma_f32_16x16x32_f16(qfrag[k], bfrag, c, 0, 0, 0);
    }
#pragma unroll
    for (int gg = 0; gg < 4; ++gg) {
      float v = (mv[nt] != 0.f) ? c[gg] : NEGV;
      rowmax[gg] = fmaxf(rowmax[gg], v);
    }
  }
#pragma unroll
  for (int off = 1; off < 16; off <<= 1) {
#pragma unroll
    for (int gg = 0; gg < 4; ++gg)
      rowmax[gg] = fmaxf(rowmax[gg], __shfl_xor(rowmax[gg], off));
  }
  if (r == 0) {
#pragma unroll
    for (int gg = 0; gg < 4; ++gg) {
      int q = qt * 16 + quad * 4 + gg;
      partials[((size_t)b * 64 + q) * 64 + dc0 + g] = rowmax[gg];
    }
  }
  // ---- folded final reduction: last block of this batch does max/sum ----
  __threadfence();
  if (tid == 0) lastflag = (atomicAdd(&counters[b], 1) == 31);
  __syncthreads();
  if (!lastflag) return;
  __threadfence();
  // 512 threads reduce partials[b]: 64 q-rows x 64 chunk-maxes
  float* red = (float*)Xs;                    // reuse LDS (sim reads done)
  {
    int q = tid >> 3, s = tid & 7;            // 8 threads per q-row
    const float4* p = (const float4*)(partials + ((size_t)b * 64 + q) * 64 + s * 8);
    float4 v0 = p[0], v1 = p[1];
    float m = fmaxf(fmaxf(fmaxf(v0.x, v0.y), fmaxf(v0.z, v0.w)),
                    fmaxf(fmaxf(v1.x, v1.y), fmaxf(v1.z, v1.w)));
    red[q * 8 + s] = m;
  }
  __syncthreads();
  if (tid < 64) {
    float qm = NEGV;
#pragma unroll
    for (int s = 0; s < 8; ++s) qm = fmaxf(qm, red[tid * 8 + s]);
    float sum = qm;
#pragma unroll
    for (int off = 1; off < 64; off <<= 1) sum += __shfl_xor(sum, off);
    if (tid == 0) out[b] = sum;
  }
}

// ---------- launch ----------

extern "C" void kernel_launch(void* const* d_in, const int* in_sizes, int n_in,
                              void* d_out, int out_size, void* d_ws, size_t ws_size,
                              hipStream_t stream) {
  const int* query_ids  = (const int*)d_in[0];
  const int* doc_ids    = (const int*)d_in[1];
  const int* query_mask = (const int*)d_in[2];
  const int* doc_mask   = (const int*)d_in[3];
  const float* q_emb = (const float*)d_in[4];
  const float* qW1 = (const float*)d_in[5];
  const float* qb1 = (const float*)d_in[6];
  const float* qW2 = (const float*)d_in[7];
  const float* qb2 = (const float*)d_in[8];
  const float* q_lnw = (const float*)d_in[9];
  const float* q_lnb = (const float*)d_in[10];
  const float* d_emb = (const float*)d_in[11];
  const float* dW1 = (const float*)d_in[12];
  const float* db1 = (const float*)d_in[13];
  const float* dW2 = (const float*)d_in[14];
  const float* db2 = (const float*)d_in[15];
  const float* d_lnw = (const float*)d_in[16];
  const float* d_lnb = (const float*)d_in[17];

  char* ws = (char*)d_ws;
  f16* wts  = (f16*)(ws + 0);            // dW1f/dW2f fragment-ordered = 64 KB
  f16* dW1f = wts;
  f16* dW2f = wts + 16384;
  f16* qv   = (f16*)(ws + 65536);        // [64][1024][8] f16 = 1 MB
  float* partials = (float*)(ws + 65536 + 1048576);   // [64][64][64] f32 = 1 MB
  int* counters   = (int*)(ws + 65536 + 2097152);     // 64 ints
  float* out = (float*)d_out;

  hipMemsetAsync(counters, 0, 64 * sizeof(int), stream);
  setup_kernel<<<80, 256, 0, stream>>>(dW1, dW2, query_ids, query_mask, q_emb,
                                       qW1, qb1, qW2, qb2, q_lnw, q_lnb,
                                       wts, qv);
  docsim_kernel<<<2048, 512, 0, stream>>>(doc_ids, doc_mask, d_emb,
                                          dW1f, db1, dW2f, db2, d_lnw, d_lnb,
                                          qv, partials, counters, out);
}

// Round 7
// 149.716 us; speedup vs baseline: 4.5075x; 4.5075x over previous
//
#include <hip/hip_runtime.h>

typedef _Float16 f16;
typedef __attribute__((ext_vector_type(8))) _Float16 f16x8;
typedef __attribute__((ext_vector_type(4))) float f32x4;

#define XS 136            // padded LDS row stride in f16 elems (128 + 8)
#define NEGV (-1e30f)

// ---------- helpers ----------

// rows x 128 f32 -> f16 LDS. thread: row tid/4 (wave-private rows).
__device__ __forceinline__ void emb_to_xs(const float* __restrict__ row_src,
                                          f16* Xs, int myrow, int seg) {
  const float4* src = (const float4*)(row_src + seg * 32);
  f16x8* dst = (f16x8*)(Xs + myrow * XS + seg * 32);
#pragma unroll
  for (int i = 0; i < 4; ++i) {
    float4 v0 = src[2 * i], v1 = src[2 * i + 1];
    f16x8 o;
    o[0] = (f16)v0.x; o[1] = (f16)v0.y; o[2] = (f16)v0.z; o[3] = (f16)v0.w;
    o[4] = (f16)v1.x; o[5] = (f16)v1.y; o[6] = (f16)v1.z; o[7] = (f16)v1.w;
    dst[i] = o;
  }
}

__device__ __forceinline__ void load_afrag(f16x8* afrag, const f16* Xs,
                                           int wave, int lane) {
  const int r = lane & 15, quad = lane >> 4;
#pragma unroll
  for (int k = 0; k < 4; ++k)
    afrag[k] = *(const f16x8*)(Xs + (wave * 16 + r) * XS + quad * 8 + k * 32);
}

// layer GEMM, B-fragments gathered inline from f32 W[k][n] (encode pass only;
// W tables are 64KB and L2-resident — latency-tolerant blocks).
__device__ __forceinline__ void layer_mfma_inline(f32x4* acc, const f16x8* afrag,
                                                  const float* __restrict__ W,
                                                  int lane) {
  const int r = lane & 15, quad = lane >> 4;
#pragma unroll
  for (int nt = 0; nt < 8; ++nt) {
    f32x4 c = {0.f, 0.f, 0.f, 0.f};
#pragma unroll
    for (int k = 0; k < 4; ++k) {
      const float* src = W + (k * 32 + quad * 8) * 128 + nt * 16 + r;
      f16x8 b;
#pragma unroll
      for (int j = 0; j < 8; ++j) b[j] = (f16)src[j * 128];
      c = __builtin_amdgcn_mfma_f32_16x16x32_f16(afrag[k], b, c, 0, 0, 0);
    }
    acc[nt] = c;
  }
}

// bias + relu + layernorm, write h back to Xs (wave-private rows)
__device__ __forceinline__ void epilogue_ln(f32x4* acc, int wave, int lane, f16* Xs,
                                            const float* __restrict__ bias,
                                            const float* __restrict__ lnw,
                                            const float* __restrict__ lnb) {
  const int r = lane & 15, quad = lane >> 4;
  float s1[4] = {0, 0, 0, 0}, s2[4] = {0, 0, 0, 0};
#pragma unroll
  for (int nt = 0; nt < 8; ++nt) {
    float bv = bias[nt * 16 + r];
#pragma unroll
    for (int g = 0; g < 4; ++g) {
      float z = fmaxf(acc[nt][g] + bv, 0.f);
      acc[nt][g] = z; s1[g] += z; s2[g] += z * z;
    }
  }
#pragma unroll
  for (int off = 1; off < 16; off <<= 1) {
#pragma unroll
    for (int g = 0; g < 4; ++g) {
      s1[g] += __shfl_xor(s1[g], off);
      s2[g] += __shfl_xor(s2[g], off);
    }
  }
  float mean[4], rstd[4];
#pragma unroll
  for (int g = 0; g < 4; ++g) {
    mean[g] = s1[g] * (1.f / 128.f);
    rstd[g] = rsqrtf(s2[g] * (1.f / 128.f) - mean[g] * mean[g] + 1e-5f);
  }
#pragma unroll
  for (int nt = 0; nt < 8; ++nt) {
    float w = lnw[nt * 16 + r], bb = lnb[nt * 16 + r];
#pragma unroll
    for (int g = 0; g < 4; ++g) {
      float h = (acc[nt][g] - mean[g]) * rstd[g] * w + bb;
      Xs[(wave * 16 + quad * 4 + g) * XS + nt * 16 + r] = (f16)h;
    }
  }
}

// ---------- kernels ----------

// blocks 0..499: encode the ENTIRE doc vocab (32000 rows) -> dvt[32000][128] f16.
// blocks 500..563: encode the 64 query batches -> qv (A-fragment order, masked).
__global__ __launch_bounds__(256) void encode_kernel(
    const int* __restrict__ qids, const int* __restrict__ qmask,
    const float* __restrict__ q_emb, const float* __restrict__ d_emb,
    const float* __restrict__ qW1, const float* __restrict__ qb1,
    const float* __restrict__ qW2, const float* __restrict__ qb2,
    const float* __restrict__ q_lnw, const float* __restrict__ q_lnb,
    const float* __restrict__ dW1, const float* __restrict__ db1,
    const float* __restrict__ dW2, const float* __restrict__ db2,
    const float* __restrict__ d_lnw, const float* __restrict__ d_lnb,
    f16* __restrict__ qv, f16* __restrict__ dvt) {
  __shared__ __align__(16) f16 Xs[64 * XS];
  const int tid = threadIdx.x, wave = tid >> 6, lane = tid & 63;
  const int myrow = tid >> 2, seg = tid & 3;
  f32x4 acc[8];
  f16x8 afrag[4];
  if (blockIdx.x < 500) {
    // ---- d-vocab encode: rows v0..v0+63, emb reads fully coalesced ----
    const int v0 = blockIdx.x * 64;
    emb_to_xs(d_emb + (size_t)(v0 + myrow) * 128, Xs, myrow, seg);
    load_afrag(afrag, Xs, wave, lane);        // own rows — no barrier
    layer_mfma_inline(acc, afrag, dW1, lane);
    epilogue_ln(acc, wave, lane, Xs, db1, d_lnw, d_lnb);
    load_afrag(afrag, Xs, wave, lane);
    layer_mfma_inline(acc, afrag, dW2, lane);
    epilogue_ln(acc, wave, lane, Xs, db2, d_lnw, d_lnb);
    // copy-out own-wave rows (row-major, coalesced) — no barrier needed
    f16x8* dst = (f16x8*)(dvt + (size_t)(v0 + myrow) * 128 + seg * 32);
    const f16x8* src = (const f16x8*)(Xs + myrow * XS + seg * 32);
#pragma unroll
    for (int i = 0; i < 4; ++i) dst[i] = src[i];
    return;
  }
  // ---- q-side encode ----
  const int b = blockIdx.x - 500;
  emb_to_xs(q_emb + (size_t)qids[b * 64 + myrow] * 128, Xs, myrow, seg);
  load_afrag(afrag, Xs, wave, lane);
  layer_mfma_inline(acc, afrag, qW1, lane);
  epilogue_ln(acc, wave, lane, Xs, qb1, q_lnw, q_lnb);
  load_afrag(afrag, Xs, wave, lane);
  layer_mfma_inline(acc, afrag, qW2, lane);
  epilogue_ln(acc, wave, lane, Xs, qb2, q_lnw, q_lnb);
  __syncthreads();                            // copy-out crosses waves
  // masked copy-out in A-fragment order: qv[b][u][8]
#pragma unroll
  for (int i = 0; i < 4; ++i) {
    int u = tid + i * 256;               // 1024 units of f16x8
    int r = u & 15, quad = (u >> 4) & 3, k = (u >> 6) & 3, mt = u >> 8;
    int row = mt * 16 + r;
    f16 m = (f16)(float)qmask[b * 64 + row];
    f16x8 v = *(const f16x8*)(Xs + row * XS + k * 32 + quad * 8);
#pragma unroll
    for (int j = 0; j < 8; ++j) v[j] = v[j] * m;
    *(f16x8*)(qv + (size_t)b * 8192 + (size_t)u * 8) = v;
  }
}

// 256 threads / 4 waves, 4 doc-chunks per block (1024 blocks).
// Pure gather + sim: dv rows come from the precomputed vocab table.
__global__ __launch_bounds__(256) void docsim_kernel(
    const int* __restrict__ dids, const int* __restrict__ dmask,
    const f16* __restrict__ dvt, const f16* __restrict__ qv,
    float* __restrict__ partials) {
  __shared__ __align__(16) f16 Xs[64 * XS];   // 17,408 B — the only LDS
  const int tid = threadIdx.x, wave = tid >> 6, lane = tid & 63;
  const int b = blockIdx.x >> 4;              // batch (1024 = 64 x 16)
  const int dc0 = (blockIdx.x & 15) * 4;      // first of 4 chunks
  const int myrow = tid >> 2, seg = tid & 3;
  const int r = lane & 15, quad = lane >> 4;
  // q fragments once per block
  f16x8 qfrag[4];
#pragma unroll
  for (int k = 0; k < 4; ++k) {
    int u = (wave * 4 + k) * 64 + quad * 16 + r;
    qfrag[k] = *(const f16x8*)(qv + (size_t)b * 8192 + (size_t)u * 8);
  }
  // all 4 chunk ids upfront (independent loads, hides id->gather latency)
  int myid[4];
#pragma unroll
  for (int c = 0; c < 4; ++c)
    myid[c] = dids[(size_t)b * 4096 + (dc0 + c) * 64 + myrow];
#pragma unroll
  for (int c = 0; c < 4; ++c) {
    const int dc = dc0 + c;
    // mask + gather issue early
    float mv[4];
#pragma unroll
    for (int nt = 0; nt < 4; ++nt)
      mv[nt] = (float)dmask[(size_t)b * 4096 + dc * 64 + nt * 16 + r];
    f16x8 row[4];
    {
      const f16x8* src = (const f16x8*)(dvt + (size_t)myid[c] * 128 + seg * 32);
#pragma unroll
      for (int i = 0; i < 4; ++i) row[i] = src[i];
    }
    if (c) __syncthreads();                   // prior sim reads done
    {
      f16x8* dst = (f16x8*)(Xs + myrow * XS + seg * 32);
#pragma unroll
      for (int i = 0; i < 4; ++i) dst[i] = row[i];
    }
    __syncthreads();                          // dv chunk visible to all waves
    float rowmax[4] = {NEGV, NEGV, NEGV, NEGV};
#pragma unroll
    for (int nt = 0; nt < 4; ++nt) {
      f32x4 cc = {0.f, 0.f, 0.f, 0.f};
#pragma unroll
      for (int k = 0; k < 4; ++k) {
        f16x8 bfrag = *(const f16x8*)(Xs + (nt * 16 + r) * XS + quad * 8 + k * 32);
        cc = __builtin_amdgcn_mfma_f32_16x16x32_f16(qfrag[k], bfrag, cc, 0, 0, 0);
      }
#pragma unroll
      for (int g = 0; g < 4; ++g) {
        float v = (mv[nt] != 0.f) ? cc[g] : NEGV;
        rowmax[g] = fmaxf(rowmax[g], v);
      }
    }
#pragma unroll
    for (int off = 1; off < 16; off <<= 1) {
#pragma unroll
      for (int g = 0; g < 4; ++g)
        rowmax[g] = fmaxf(rowmax[g], __shfl_xor(rowmax[g], off));
    }
    if (r == 0) {
#pragma unroll
      for (int g = 0; g < 4; ++g) {
        int q = wave * 16 + quad * 4 + g;
        partials[((size_t)b * 64 + q) * 64 + dc] = rowmax[g];
      }
    }
  }
}

__global__ __launch_bounds__(256) void reduce_kernel(
    const float* __restrict__ partials, float* __restrict__ out) {
  __shared__ float red[64][4];
  const int b = blockIdx.x, tid = threadIdx.x;
  const int q = tid >> 2, seg = tid & 3;
  const float4* p = (const float4*)(partials + ((size_t)b * 64 + q) * 64 + seg * 16);
  float m = NEGV;
#pragma unroll
  for (int i = 0; i < 4; ++i) {
    float4 v = p[i];
    m = fmaxf(m, fmaxf(fmaxf(v.x, v.y), fmaxf(v.z, v.w)));
  }
  red[q][seg] = m;
  __syncthreads();
  if (tid < 64) {
    float qm = fmaxf(fmaxf(red[tid][0], red[tid][1]), fmaxf(red[tid][2], red[tid][3]));
    float s = qm;
#pragma unroll
    for (int off = 1; off < 64; off <<= 1) s += __shfl_xor(s, off);
    if (tid == 0) out[b] = s;
  }
}

// ---------- launch ----------

extern "C" void kernel_launch(void* const* d_in, const int* in_sizes, int n_in,
                              void* d_out, int out_size, void* d_ws, size_t ws_size,
                              hipStream_t stream) {
  const int* query_ids  = (const int*)d_in[0];
  const int* doc_ids    = (const int*)d_in[1];
  const int* query_mask = (const int*)d_in[2];
  const int* doc_mask   = (const int*)d_in[3];
  const float* q_emb = (const float*)d_in[4];
  const float* qW1 = (const float*)d_in[5];
  const float* qb1 = (const float*)d_in[6];
  const float* qW2 = (const float*)d_in[7];
  const float* qb2 = (const float*)d_in[8];
  const float* q_lnw = (const float*)d_in[9];
  const float* q_lnb = (const float*)d_in[10];
  const float* d_emb = (const float*)d_in[11];
  const float* dW1 = (const float*)d_in[12];
  const float* db1 = (const float*)d_in[13];
  const float* dW2 = (const float*)d_in[14];
  const float* db2 = (const float*)d_in[15];
  const float* d_lnw = (const float*)d_in[16];
  const float* d_lnb = (const float*)d_in[17];

  char* ws = (char*)d_ws;
  f16* dvt = (f16*)(ws + 0);                       // [32000][128] f16 = 8.192 MB
  f16* qv  = (f16*)(ws + 8192000);                 // [64][1024][8] f16 = 1 MB
  float* partials = (float*)(ws + 8192000 + 1048576);  // [64][64][64] f32 = 1 MB
  float* out = (float*)d_out;

  encode_kernel<<<564, 256, 0, stream>>>(query_ids, query_mask, q_emb, d_emb,
                                         qW1, qb1, qW2, qb2, q_lnw, q_lnb,
                                         dW1, db1, dW2, db2, d_lnw, d_lnb,
                                         qv, dvt);
  docsim_kernel<<<1024, 256, 0, stream>>>(doc_ids, doc_mask, dvt, qv, partials);
  reduce_kernel<<<64, 256, 0, stream>>>(partials, out);
}

// Round 8
// 134.502 us; speedup vs baseline: 5.0173x; 1.1131x over previous
//
#include <hip/hip_runtime.h>

typedef _Float16 f16;
typedef __attribute__((ext_vector_type(8))) _Float16 f16x8;
typedef __attribute__((ext_vector_type(4))) float f32x4;

#define XS 136            // padded LDS row stride in f16 elems (128 + 8)
#define NEGV (-1e30f)

// ---------- helpers ----------

// async global->LDS, 16B per lane; LDS dest = wave-uniform base + lane*16
__device__ __forceinline__ void gl_lds16(const f16* g, f16* l) {
  __builtin_amdgcn_global_load_lds(
      (const __attribute__((address_space(1))) unsigned int*)(g),
      (__attribute__((address_space(3))) unsigned int*)(l), 16, 0, 0);
}

// stage a full fragment-ordered W (16384 f16 = 32KB) into LDS; 4 waves
__device__ __forceinline__ void stage_w_full(const f16* __restrict__ Wf,
                                             f16* Ws, int wave, int lane) {
#pragma unroll
  for (int c = 0; c < 8; ++c) {
    int chunk = wave * 8 + c;                 // 32 chunks of 1KB
    gl_lds16(Wf + chunk * 512 + lane * 8, Ws + chunk * 512);
  }
}

// one emb row (f32) -> f16 LDS row. thread: row tid/4 (wave-private rows).
__device__ __forceinline__ void emb_to_xs(const float* __restrict__ row_src,
                                          f16* Xs, int myrow, int seg) {
  const float4* src = (const float4*)(row_src + seg * 32);
  f16x8* dst = (f16x8*)(Xs + myrow * XS + seg * 32);
#pragma unroll
  for (int i = 0; i < 4; ++i) {
    float4 v0 = src[2 * i], v1 = src[2 * i + 1];
    f16x8 o;
    o[0] = (f16)v0.x; o[1] = (f16)v0.y; o[2] = (f16)v0.z; o[3] = (f16)v0.w;
    o[4] = (f16)v1.x; o[5] = (f16)v1.y; o[6] = (f16)v1.z; o[7] = (f16)v1.w;
    dst[i] = o;
  }
}

__device__ __forceinline__ void load_afrag(f16x8* afrag, const f16* Xs,
                                           int wave, int lane) {
  const int r = lane & 15, quad = lane >> 4;
#pragma unroll
  for (int k = 0; k < 4; ++k)
    afrag[k] = *(const f16x8*)(Xs + (wave * 16 + r) * XS + quad * 8 + k * 32);
}

// layer GEMM, B-fragments from LDS (conflict-free contiguous ds_read_b128)
__device__ __forceinline__ void layer_mfma_lds(f32x4* acc, const f16x8* afrag,
                                               const f16* Ws, int lane) {
  const f16* Wl = Ws + lane * 8;
#pragma unroll
  for (int nt = 0; nt < 8; ++nt) {
    f32x4 c = {0.f, 0.f, 0.f, 0.f};
#pragma unroll
    for (int k = 0; k < 4; ++k) {
      f16x8 b = *(const f16x8*)(Wl + (nt * 4 + k) * 512);
      c = __builtin_amdgcn_mfma_f32_16x16x32_f16(afrag[k], b, c, 0, 0, 0);
    }
    acc[nt] = c;
  }
}

// bias + relu + layernorm, write h back to Xs (wave-private rows)
__device__ __forceinline__ void epilogue_ln(f32x4* acc, int wave, int lane, f16* Xs,
                                            const float* __restrict__ bias,
                                            const float* __restrict__ lnw,
                                            const float* __restrict__ lnb) {
  const int r = lane & 15, quad = lane >> 4;
  float s1[4] = {0, 0, 0, 0}, s2[4] = {0, 0, 0, 0};
#pragma unroll
  for (int nt = 0; nt < 8; ++nt) {
    float bv = bias[nt * 16 + r];
#pragma unroll
    for (int g = 0; g < 4; ++g) {
      float z = fmaxf(acc[nt][g] + bv, 0.f);
      acc[nt][g] = z; s1[g] += z; s2[g] += z * z;
    }
  }
#pragma unroll
  for (int off = 1; off < 16; off <<= 1) {
#pragma unroll
    for (int g = 0; g < 4; ++g) {
      s1[g] += __shfl_xor(s1[g], off);
      s2[g] += __shfl_xor(s2[g], off);
    }
  }
  float mean[4], rstd[4];
#pragma unroll
  for (int g = 0; g < 4; ++g) {
    mean[g] = s1[g] * (1.f / 128.f);
    rstd[g] = rsqrtf(s2[g] * (1.f / 128.f) - mean[g] * mean[g] + 1e-5f);
  }
#pragma unroll
  for (int nt = 0; nt < 8; ++nt) {
    float w = lnw[nt * 16 + r], bb = lnb[nt * 16 + r];
#pragma unroll
    for (int g = 0; g < 4; ++g) {
      float h = (acc[nt][g] - mean[g]) * rstd[g] * w + bb;
      Xs[(wave * 16 + quad * 4 + g) * XS + nt * 16 + r] = (f16)h;
    }
  }
}

// ---------- kernels ----------

// W[k][n] f32 -> fragment-ordered f16: out[((nt*4+k)*64 + quad*16 + r)*8 + j]
//   = W[k*32 + quad*8 + j][nt*16 + r].  4 matrices x 8 blocks.
__global__ __launch_bounds__(256) void prep_kernel(
    const float* __restrict__ qW1, const float* __restrict__ qW2,
    const float* __restrict__ dW1, const float* __restrict__ dW2,
    f16* __restrict__ out) {
  int mat = blockIdx.x >> 3;
  int blk = blockIdx.x & 7;
  const float* W = mat == 0 ? qW1 : mat == 1 ? qW2 : mat == 2 ? dW1 : dW2;
  int u = blk * 256 + threadIdx.x;
  int r = u & 15, quad = (u >> 4) & 3, k = (u >> 6) & 3, nt = u >> 8;
  const float* src = W + (k * 32 + quad * 8) * 128 + nt * 16 + r;
  f16x8 o;
#pragma unroll
  for (int j = 0; j < 8; ++j) o[j] = (f16)src[j * 128];
  *(f16x8*)(out + (size_t)mat * 16384 + (size_t)u * 8) = o;
}

// blocks 0..499: encode the ENTIRE doc vocab (32000 rows) -> dvt[32000][128] f16.
// blocks 500..563: encode the 64 query batches -> qv (A-fragment order, masked).
// W staged via async DMA from fragment-ordered tables; 3 barriers.
__global__ __launch_bounds__(256) void encode_kernel(
    const int* __restrict__ qids, const int* __restrict__ qmask,
    const float* __restrict__ q_emb, const float* __restrict__ d_emb,
    const f16* __restrict__ qW1f, const float* __restrict__ qb1,
    const f16* __restrict__ qW2f, const float* __restrict__ qb2,
    const float* __restrict__ q_lnw, const float* __restrict__ q_lnb,
    const f16* __restrict__ dW1f, const float* __restrict__ db1,
    const f16* __restrict__ dW2f, const float* __restrict__ db2,
    const float* __restrict__ d_lnw, const float* __restrict__ d_lnb,
    f16* __restrict__ qv, f16* __restrict__ dvt) {
  __shared__ __align__(16) f16 Xs[64 * XS];   // 17,408 B
  __shared__ __align__(16) f16 Ws[16384];     // 32,768 B
  const int tid = threadIdx.x, wave = tid >> 6, lane = tid & 63;
  const int myrow = tid >> 2, seg = tid & 3;
  const bool dside = blockIdx.x < 500;
  const int b = dside ? 0 : blockIdx.x - 500;
  const int v0 = blockIdx.x * 64;

  const f16* W1f = dside ? dW1f : qW1f;
  const f16* W2f = dside ? dW2f : qW2f;
  const float* b1 = dside ? db1 : qb1;
  const float* b2 = dside ? db2 : qb2;
  const float* lnw = dside ? d_lnw : q_lnw;
  const float* lnb = dside ? d_lnb : q_lnb;

  stage_w_full(W1f, Ws, wave, lane);          // async DMA
  if (dside) emb_to_xs(d_emb + (size_t)(v0 + myrow) * 128, Xs, myrow, seg);
  else       emb_to_xs(q_emb + (size_t)qids[b * 64 + myrow] * 128, Xs, myrow, seg);
  __syncthreads();                            // W1 staged (+ all Xs rows)
  f32x4 acc[8];
  f16x8 afrag[4];
  load_afrag(afrag, Xs, wave, lane);
  layer_mfma_lds(acc, afrag, Ws, lane);
  __syncthreads();                            // Ws reads done
  stage_w_full(W2f, Ws, wave, lane);          // async; overlaps epilogue
  epilogue_ln(acc, wave, lane, Xs, b1, lnw, lnb);
  __syncthreads();                            // W2 staged
  load_afrag(afrag, Xs, wave, lane);
  layer_mfma_lds(acc, afrag, Ws, lane);
  epilogue_ln(acc, wave, lane, Xs, b2, lnw, lnb);
  if (dside) {
    // copy-out own-wave rows (row-major, coalesced) — no barrier needed
    f16x8* dst = (f16x8*)(dvt + (size_t)(v0 + myrow) * 128 + seg * 32);
    const f16x8* src = (const f16x8*)(Xs + myrow * XS + seg * 32);
#pragma unroll
    for (int i = 0; i < 4; ++i) dst[i] = src[i];
    return;
  }
  __syncthreads();                            // copy-out crosses waves
  // masked copy-out in A-fragment order: qv[b][u][8]
#pragma unroll
  for (int i = 0; i < 4; ++i) {
    int u = tid + i * 256;               // 1024 units of f16x8
    int r = u & 15, quad = (u >> 4) & 3, k = (u >> 6) & 3, mt = u >> 8;
    int row = mt * 16 + r;
    f16 m = (f16)(float)qmask[b * 64 + row];
    f16x8 v = *(const f16x8*)(Xs + row * XS + k * 32 + quad * 8);
#pragma unroll
    for (int j = 0; j < 8; ++j) v[j] = v[j] * m;
    *(f16x8*)(qv + (size_t)b * 8192 + (size_t)u * 8) = v;
  }
}

// 256 threads / 4 waves, 4 doc-chunks per block (1024 blocks).
// Pure gather + sim: dv rows come from the precomputed vocab table.
__global__ __launch_bounds__(256) void docsim_kernel(
    const int* __restrict__ dids, const int* __restrict__ dmask,
    const f16* __restrict__ dvt, const f16* __restrict__ qv,
    float* __restrict__ partials) {
  __shared__ __align__(16) f16 Xs[64 * XS];   // 17,408 B — the only LDS
  const int tid = threadIdx.x, wave = tid >> 6, lane = tid & 63;
  const int b = blockIdx.x >> 4;              // batch (1024 = 64 x 16)
  const int dc0 = (blockIdx.x & 15) * 4;      // first of 4 chunks
  const int myrow = tid >> 2, seg = tid & 3;
  const int r = lane & 15, quad = lane >> 4;
  // q fragments once per block
  f16x8 qfrag[4];
#pragma unroll
  for (int k = 0; k < 4; ++k) {
    int u = (wave * 4 + k) * 64 + quad * 16 + r;
    qfrag[k] = *(const f16x8*)(qv + (size_t)b * 8192 + (size_t)u * 8);
  }
  // all 4 chunk ids upfront (independent loads, hides id->gather latency)
  int myid[4];
#pragma unroll
  for (int c = 0; c < 4; ++c)
    myid[c] = dids[(size_t)b * 4096 + (dc0 + c) * 64 + myrow];
#pragma unroll
  for (int c = 0; c < 4; ++c) {
    const int dc = dc0 + c;
    float mv[4];
#pragma unroll
    for (int nt = 0; nt < 4; ++nt)
      mv[nt] = (float)dmask[(size_t)b * 4096 + dc * 64 + nt * 16 + r];
    f16x8 row[4];
    {
      const f16x8* src = (const f16x8*)(dvt + (size_t)myid[c] * 128 + seg * 32);
#pragma unroll
      for (int i = 0; i < 4; ++i) row[i] = src[i];
    }
    if (c) __syncthreads();                   // prior sim reads done
    {
      f16x8* dst = (f16x8*)(Xs + myrow * XS + seg * 32);
#pragma unroll
      for (int i = 0; i < 4; ++i) dst[i] = row[i];
    }
    __syncthreads();                          // dv chunk visible to all waves
    float rowmax[4] = {NEGV, NEGV, NEGV, NEGV};
#pragma unroll
    for (int nt = 0; nt < 4; ++nt) {
      f32x4 cc = {0.f, 0.f, 0.f, 0.f};
#pragma unroll
      for (int k = 0; k < 4; ++k) {
        f16x8 bfrag = *(const f16x8*)(Xs + (nt * 16 + r) * XS + quad * 8 + k * 32);
        cc = __builtin_amdgcn_mfma_f32_16x16x32_f16(qfrag[k], bfrag, cc, 0, 0, 0);
      }
#pragma unroll
      for (int g = 0; g < 4; ++g) {
        float v = (mv[nt] != 0.f) ? cc[g] : NEGV;
        rowmax[g] = fmaxf(rowmax[g], v);
      }
    }
#pragma unroll
    for (int off = 1; off < 16; off <<= 1) {
#pragma unroll
      for (int g = 0; g < 4; ++g)
        rowmax[g] = fmaxf(rowmax[g], __shfl_xor(rowmax[g], off));
    }
    if (r == 0) {
#pragma unroll
      for (int g = 0; g < 4; ++g) {
        int q = wave * 16 + quad * 4 + g;
        partials[((size_t)b * 64 + q) * 64 + dc] = rowmax[g];
      }
    }
  }
}

__global__ __launch_bounds__(256) void reduce_kernel(
    const float* __restrict__ partials, float* __restrict__ out) {
  __shared__ float red[64][4];
  const int b = blockIdx.x, tid = threadIdx.x;
  const int q = tid >> 2, seg = tid & 3;
  const float4* p = (const float4*)(partials + ((size_t)b * 64 + q) * 64 + seg * 16);
  float m = NEGV;
#pragma unroll
  for (int i = 0; i < 4; ++i) {
    float4 v = p[i];
    m = fmaxf(m, fmaxf(fmaxf(v.x, v.y), fmaxf(v.z, v.w)));
  }
  red[q][seg] = m;
  __syncthreads();
  if (tid < 64) {
    float qm = fmaxf(fmaxf(red[tid][0], red[tid][1]), fmaxf(red[tid][2], red[tid][3]));
    float s = qm;
#pragma unroll
    for (int off = 1; off < 64; off <<= 1) s += __shfl_xor(s, off);
    if (tid == 0) out[b] = s;
  }
}

// ---------- launch ----------

extern "C" void kernel_launch(void* const* d_in, const int* in_sizes, int n_in,
                              void* d_out, int out_size, void* d_ws, size_t ws_size,
                              hipStream_t stream) {
  const int* query_ids  = (const int*)d_in[0];
  const int* doc_ids    = (const int*)d_in[1];
  const int* query_mask = (const int*)d_in[2];
  const int* doc_mask   = (const int*)d_in[3];
  const float* q_emb = (const float*)d_in[4];
  const float* qW1 = (const float*)d_in[5];
  const float* qb1 = (const float*)d_in[6];
  const float* qW2 = (const float*)d_in[7];
  const float* qb2 = (const float*)d_in[8];
  const float* q_lnw = (const float*)d_in[9];
  const float* q_lnb = (const float*)d_in[10];
  const float* d_emb = (const float*)d_in[11];
  const float* dW1 = (const float*)d_in[12];
  const float* db1 = (const float*)d_in[13];
  const float* dW2 = (const float*)d_in[14];
  const float* db2 = (const float*)d_in[15];
  const float* d_lnw = (const float*)d_in[16];
  const float* d_lnb = (const float*)d_in[17];

  char* ws = (char*)d_ws;
  f16* wts  = (f16*)(ws + 0);            // 4 x 16384 f16 fragment-ordered = 128 KB
  f16* qW1f = wts;
  f16* qW2f = wts + 16384;
  f16* dW1f = wts + 32768;
  f16* dW2f = wts + 49152;
  f16* dvt = (f16*)(ws + 131072);                      // [32000][128] f16 = 8.192 MB
  f16* qv  = (f16*)(ws + 131072 + 8192000);            // [64][1024][8] f16 = 1 MB
  float* partials = (float*)(ws + 131072 + 8192000 + 1048576);  // 1 MB
  float* out = (float*)d_out;

  prep_kernel<<<32, 256, 0, stream>>>(qW1, qW2, dW1, dW2, wts);
  encode_kernel<<<564, 256, 0, stream>>>(query_ids, query_mask, q_emb, d_emb,
                                         qW1f, qb1, qW2f, qb2, q_lnw, q_lnb,
                                         dW1f, db1, dW2f, db2, d_lnw, d_lnb,
                                         qv, dvt);
  docsim_kernel<<<1024, 256, 0, stream>>>(doc_ids, doc_mask, dvt, qv, partials);
  reduce_kernel<<<64, 256, 0, stream>>>(partials, out);
}